// Round 3
// baseline (1268.502 us; speedup 1.0000x reference)
//
#include <hip/hip_runtime.h>
#include <math.h>

// Problem constants (B=4, T=4096, D_MODEL=1024, H=16, D_HEAD=64, MEM=256)
constexpr int B_  = 4;
constexpr int T_  = 4096;
constexpr int DM_ = 1024;
constexpr int H_  = 16;
constexpr int S_  = 256;
constexpr int BT_ = B_ * T_;                    // 16384
constexpr int NTILE_ = T_ / 64;                 // 64 token-tiles per (b,h)
constexpr size_t QELEMS = (size_t)BT_ * DM_;    // 16,777,216 floats (64 MiB)
constexpr size_t PELEMS = (size_t)B_ * H_ * T_ * S_;  // 67,108,864 floats (256 MiB)
                                                // NOTE: P is 4x out_size — this
                                                // was the rounds-0..2 OOB fault.

// Static device scratch; every element is rewritten each call before any read.
__device__ float g_Q[QELEMS];                          // Q, reused as out_pre
__device__ float g_P[PELEMS];                          // attn probabilities
__device__ float g_cpart[(size_t)B_ * H_ * NTILE_ * S_];  // per-tile colsum partials
__device__ float g_colsum_inv[B_ * H_ * S_];           // 1/(colsum + 1e-6)

// ---------------------------------------------------------------------------
// GEMM body: C[m,n] = sum_k A[m,k] * W[n,k]   (A @ W^T, row-major)
// M=16384, N=1024, K=1024. Tile 128(M) x 64(N) x 16(K), 256 thr, 8x4/thread.
// ---------------------------------------------------------------------------
__device__ __forceinline__ void gemm_body(const float* __restrict__ A,
                                          const float* __restrict__ W,
                                          float* __restrict__ C) {
  __shared__ float As[16][128];   // [k][m]
  __shared__ float Ws[16][64];    // [k][n]
  const int tid = threadIdx.x;
  const int m0 = blockIdx.x * 128;
  const int n0 = blockIdx.y * 64;
  const int ty = tid >> 4;        // 0..15 -> m_base = ty*8
  const int tx = tid & 15;        // 0..15 -> n_base = tx*4
  float acc[8][4] = {};
  for (int k0 = 0; k0 < 1024; k0 += 16) {
#pragma unroll
    for (int i = 0; i < 2; ++i) {
      int c  = i * 256 + tid;      // 512 float4 chunks
      int m  = c >> 2;
      int kc = (c & 3) * 4;
      float4 v = *(const float4*)&A[(size_t)(m0 + m) * 1024 + (k0 + kc)];
      As[kc + 0][m] = v.x; As[kc + 1][m] = v.y;
      As[kc + 2][m] = v.z; As[kc + 3][m] = v.w;
    }
    {
      int n  = tid >> 2;
      int kc = (tid & 3) * 4;
      float4 v = *(const float4*)&W[(size_t)(n0 + n) * 1024 + (k0 + kc)];
      Ws[kc + 0][n] = v.x; Ws[kc + 1][n] = v.y;
      Ws[kc + 2][n] = v.z; Ws[kc + 3][n] = v.w;
    }
    __syncthreads();
#pragma unroll
    for (int k = 0; k < 16; ++k) {
      float a[8], w[4];
      *(float4*)&a[0] = *(const float4*)&As[k][ty * 8];
      *(float4*)&a[4] = *(const float4*)&As[k][ty * 8 + 4];
      *(float4*)&w[0] = *(const float4*)&Ws[k][tx * 4];
#pragma unroll
      for (int i = 0; i < 8; ++i)
#pragma unroll
        for (int j = 0; j < 4; ++j)
          acc[i][j] = fmaf(a[i], w[j], acc[i][j]);
    }
    __syncthreads();
  }
#pragma unroll
  for (int i = 0; i < 8; ++i) {
    float4 v = make_float4(acc[i][0], acc[i][1], acc[i][2], acc[i][3]);
    *(float4*)&C[(size_t)(m0 + ty * 8 + i) * 1024 + (n0 + tx * 4)] = v;
  }
}

// Wrappers referencing device globals directly (no host symbol lookups).
__global__ __launch_bounds__(256) void gemm_q(const float* __restrict__ x,
                                              const float* __restrict__ Wq) {
  gemm_body(x, Wq, g_Q);
}
__global__ __launch_bounds__(256) void gemm_o(const float* __restrict__ Wo,
                                              float* __restrict__ out) {
  gemm_body(g_Q, Wo, out);
}

// ---------------------------------------------------------------------------
// Attention pass 1: logits = Q_head . M_k^T / 8, softmax over S, write g_P,
// write per-tile colsum partials (no global atomics).
// Block = one (b,h) x 64-token tile. 256 threads.
// Thread (tg=tid>>5, sg=tid&31) owns 8 tokens x 8 s (s = sg+32j).
// ---------------------------------------------------------------------------
__global__ __launch_bounds__(256) void attn_softmax_colsum(
    const float* __restrict__ Mk) {
  __shared__ float QsT[64][68];    // [d][t]
  __shared__ float MkT[32][257];   // [d-chunk][s]
  __shared__ float csum_sh[256];
  const int tid = threadIdx.x;
  const int bh  = blockIdx.x;      // b*16 + h
  const int b   = bh >> 4, h = bh & 15;
  const int t0  = blockIdx.y * 64;
  const int tg  = tid >> 5;        // 0..7
  const int sg  = tid & 31;        // 0..31

  csum_sh[tid] = 0.0f;
#pragma unroll
  for (int i = 0; i < 4; ++i) {
    int c  = i * 256 + tid;        // 1024 float4 chunks
    int t  = c >> 4;               // 0..63
    int dc = (c & 15) * 4;
    float4 v = *(const float4*)&g_Q[(size_t)(b * T_ + t0 + t) * 1024 + h * 64 + dc];
    QsT[dc + 0][t] = v.x; QsT[dc + 1][t] = v.y;
    QsT[dc + 2][t] = v.z; QsT[dc + 3][t] = v.w;
  }

  float acc[8][8] = {};
  for (int dchunk = 0; dchunk < 2; ++dchunk) {
    __syncthreads();
#pragma unroll
    for (int i = 0; i < 8; ++i) {
      int c  = i * 256 + tid;      // 2048 float4 chunks
      int s  = c >> 3;             // 0..255
      int dc = (c & 7) * 4;        // 0..28
      float4 v = *(const float4*)&Mk[(size_t)(h * 256 + s) * 64 + dchunk * 32 + dc];
      MkT[dc + 0][s] = v.x; MkT[dc + 1][s] = v.y;
      MkT[dc + 2][s] = v.z; MkT[dc + 3][s] = v.w;
    }
    __syncthreads();
    for (int d = 0; d < 32; ++d) {
      float q[8], mk[8];
      *(float4*)&q[0] = *(const float4*)&QsT[dchunk * 32 + d][tg * 8];
      *(float4*)&q[4] = *(const float4*)&QsT[dchunk * 32 + d][tg * 8 + 4];
#pragma unroll
      for (int j = 0; j < 8; ++j) mk[j] = MkT[d][sg + 32 * j];
#pragma unroll
      for (int i = 0; i < 8; ++i)
#pragma unroll
        for (int j = 0; j < 8; ++j)
          acc[i][j] = fmaf(q[i], mk[j], acc[i][j]);
    }
  }

  const float scale = 0.125f;  // D^-0.5
  float colacc[8] = {};
#pragma unroll
  for (int i = 0; i < 8; ++i) {
    float m = -INFINITY;
#pragma unroll
    for (int j = 0; j < 8; ++j) { acc[i][j] *= scale; m = fmaxf(m, acc[i][j]); }
#pragma unroll
    for (int off = 16; off >= 1; off >>= 1) m = fmaxf(m, __shfl_xor(m, off));
    float ssum = 0.0f;
#pragma unroll
    for (int j = 0; j < 8; ++j) { acc[i][j] = expf(acc[i][j] - m); ssum += acc[i][j]; }
#pragma unroll
    for (int off = 16; off >= 1; off >>= 1) ssum += __shfl_xor(ssum, off);
    const float inv = 1.0f / ssum;
    const int t = t0 + tg * 8 + i;
    float* Prow = &g_P[((size_t)bh * T_ + t) * 256];
#pragma unroll
    for (int j = 0; j < 8; ++j) {
      float p = acc[i][j] * inv;
      Prow[sg + 32 * j] = p;          // coalesced along s
      colacc[j] += p;
    }
  }
#pragma unroll
  for (int j = 0; j < 8; ++j) atomicAdd(&csum_sh[sg + 32 * j], colacc[j]);
  __syncthreads();
  g_cpart[((size_t)bh * NTILE_ + blockIdx.y) * 256 + tid] = csum_sh[tid];
}

// ---------------------------------------------------------------------------
// Fold the 64 per-tile partials into 1/(colsum + 1e-6). 64 blocks x 256 thr.
// ---------------------------------------------------------------------------
__global__ __launch_bounds__(256) void reduce_colsum() {
  const int bh = blockIdx.x;
  const int s  = threadIdx.x;
  float acc = 0.0f;
#pragma unroll 8
  for (int k = 0; k < NTILE_; ++k)
    acc += g_cpart[((size_t)bh * NTILE_ + k) * 256 + s];
  g_colsum_inv[bh * 256 + s] = 1.0f / (acc + 1e-6f);
}

// ---------------------------------------------------------------------------
// out_pre[b,t,h*64+d] = sum_s g_P[b,h,t,s] * g_colsum_inv[b,h,s] * Mv[h,s,d]
// Block = one (b,h) x 64-token tile; 64x64 output tile, 4x4/thread.
// Writes out_pre into g_Q (Q is dead by now).
// ---------------------------------------------------------------------------
__global__ __launch_bounds__(256) void pv_norm(const float* __restrict__ Mv) {
  __shared__ float Ps[64][64];     // [t][s-chunk]
  __shared__ float Mvs[64][64];    // [s-chunk][d]
  __shared__ float inv_sh[256];
  const int tid = threadIdx.x;
  const int bh  = blockIdx.x;
  const int b   = bh >> 4, h = bh & 15;
  const int t0  = blockIdx.y * 64;
  const int tg  = tid >> 4;        // 0..15 -> t = tg*4+i
  const int dg  = tid & 15;        // 0..15 -> d = dg*4+j
  inv_sh[tid] = g_colsum_inv[bh * 256 + tid];

  float acc[4][4] = {};
  for (int sc = 0; sc < 4; ++sc) {
    __syncthreads();
#pragma unroll
    for (int i = 0; i < 4; ++i) {
      int c   = i * 256 + tid;     // 1024 float4
      int t   = c >> 4;
      int scl = (c & 15) * 4;
      float4 v = *(const float4*)&g_P[((size_t)bh * T_ + t0 + t) * 256 + sc * 64 + scl];
      Ps[t][scl + 0] = v.x * inv_sh[sc * 64 + scl + 0];
      Ps[t][scl + 1] = v.y * inv_sh[sc * 64 + scl + 1];
      Ps[t][scl + 2] = v.z * inv_sh[sc * 64 + scl + 2];
      Ps[t][scl + 3] = v.w * inv_sh[sc * 64 + scl + 3];
    }
#pragma unroll
    for (int i = 0; i < 4; ++i) {
      int c   = i * 256 + tid;
      int s   = c >> 4;
      int dcl = (c & 15) * 4;
      float4 v = *(const float4*)&Mv[((size_t)h * 256 + sc * 64 + s) * 64 + dcl];
      *(float4*)&Mvs[s][dcl] = v;
    }
    __syncthreads();
    for (int s = 0; s < 64; ++s) {
      float p0 = Ps[tg * 4 + 0][s];
      float p1 = Ps[tg * 4 + 1][s];
      float p2 = Ps[tg * 4 + 2][s];
      float p3 = Ps[tg * 4 + 3][s];
      float4 mv = *(const float4*)&Mvs[s][dg * 4];
      acc[0][0] = fmaf(p0, mv.x, acc[0][0]); acc[0][1] = fmaf(p0, mv.y, acc[0][1]);
      acc[0][2] = fmaf(p0, mv.z, acc[0][2]); acc[0][3] = fmaf(p0, mv.w, acc[0][3]);
      acc[1][0] = fmaf(p1, mv.x, acc[1][0]); acc[1][1] = fmaf(p1, mv.y, acc[1][1]);
      acc[1][2] = fmaf(p1, mv.z, acc[1][2]); acc[1][3] = fmaf(p1, mv.w, acc[1][3]);
      acc[2][0] = fmaf(p2, mv.x, acc[2][0]); acc[2][1] = fmaf(p2, mv.y, acc[2][1]);
      acc[2][2] = fmaf(p2, mv.z, acc[2][2]); acc[2][3] = fmaf(p2, mv.w, acc[2][3]);
      acc[3][0] = fmaf(p3, mv.x, acc[3][0]); acc[3][1] = fmaf(p3, mv.y, acc[3][1]);
      acc[3][2] = fmaf(p3, mv.z, acc[3][2]); acc[3][3] = fmaf(p3, mv.w, acc[3][3]);
    }
  }
#pragma unroll
  for (int i = 0; i < 4; ++i) {
    float4 v = make_float4(acc[i][0], acc[i][1], acc[i][2], acc[i][3]);
    *(float4*)&g_Q[(size_t)(b * T_ + t0 + tg * 4 + i) * 1024 + h * 64 + dg * 4] = v;
  }
}

// ---------------------------------------------------------------------------
// Pipeline (d_out written only by the final GEMM):
//   gemm_q(x,Wq) -> g_Q
//   attn(Mk)     -> g_P, g_cpart
//   reduce       -> g_colsum_inv
//   pv(Mv)       -> g_Q (out_pre)
//   gemm_o(Wo)   -> d_out
// ---------------------------------------------------------------------------
extern "C" void kernel_launch(void* const* d_in, const int* in_sizes, int n_in,
                              void* d_out, int out_size, void* d_ws, size_t ws_size,
                              hipStream_t stream) {
  const float* x  = (const float*)d_in[0];
  const float* Wq = (const float*)d_in[1];
  const float* Wo = (const float*)d_in[2];
  const float* Mk = (const float*)d_in[3];
  const float* Mv = (const float*)d_in[4];
  float* out = (float*)d_out;

  gemm_q<<<dim3(BT_ / 128, DM_ / 64), 256, 0, stream>>>(x, Wq);
  attn_softmax_colsum<<<dim3(B_ * H_, NTILE_), 256, 0, stream>>>(Mk);
  reduce_colsum<<<dim3(B_ * H_), 256, 0, stream>>>();
  pv_norm<<<dim3(B_ * H_, NTILE_), 256, 0, stream>>>(Mv);
  gemm_o<<<dim3(BT_ / 128, DM_ / 64), 256, 0, stream>>>(Wo, out);
}

// Round 5
// 554.309 us; speedup vs baseline: 2.2884x; 2.2884x over previous
//
#include <hip/hip_runtime.h>
#include <math.h>

// Problem constants (B=4, T=4096, D_MODEL=1024, H=16, D_HEAD=64, MEM=256)
constexpr int B_  = 4;
constexpr int T_  = 4096;
constexpr int DM_ = 1024;
constexpr int H_  = 16;
constexpr int S_  = 256;
constexpr int BT_ = B_ * T_;                    // 16384
constexpr int NTILE_ = T_ / 64;                 // 64 token-tiles per (b,h)
constexpr size_t QELEMS = (size_t)BT_ * DM_;    // 16,777,216
constexpr size_t PELEMS = (size_t)B_ * H_ * T_ * S_;  // 67,108,864 (256 MiB) — 4x out_size!

typedef _Float16 v8h __attribute__((ext_vector_type(8)));
typedef _Float16 v4h __attribute__((ext_vector_type(4)));
typedef float    v4f __attribute__((ext_vector_type(4)));

// Static device scratch; every element rewritten each call before any read.
__device__ _Float16 g_AH[QELEMS];        // fp16 x, later rewritten as fp16 out_pre*512
__device__ _Float16 g_WqH[DM_ * DM_];    // fp16 Wq
__device__ _Float16 g_WoH[DM_ * DM_];    // fp16 Wo
__device__ float    g_Q[QELEMS];         // Q projection (fp32)
__device__ float    g_P[PELEMS];         // attn probabilities
__device__ float    g_cpart[(size_t)B_ * H_ * NTILE_ * S_];
__device__ float    g_colsum_inv[B_ * H_ * S_];

// ---------------------------------------------------------------------------
// fp32 -> fp16 conversion, 8 elems/thread.
// ---------------------------------------------------------------------------
__global__ __launch_bounds__(256) void cvt_h(const float* __restrict__ src,
                                             _Float16* __restrict__ dst) {
  const size_t i = (size_t)blockIdx.x * 256 + threadIdx.x;
  const float4* s = (const float4*)src;
  float4 a = s[2 * i], b = s[2 * i + 1];
  v8h o;
  o[0] = (_Float16)a.x; o[1] = (_Float16)a.y; o[2] = (_Float16)a.z; o[3] = (_Float16)a.w;
  o[4] = (_Float16)b.x; o[5] = (_Float16)b.y; o[6] = (_Float16)b.z; o[7] = (_Float16)b.w;
  *(v8h*)&dst[8 * i] = o;
}

// ---------------------------------------------------------------------------
// MFMA GEMM: C[m,n] = scale * sum_k A[m,k] * W[n,k]  (A @ W^T), fp16 in, fp32 out.
// M=16384, N=1024, K=1024. Block tile 128x128, BK=64, 256 thr = 4 waves (2x2).
// Each wave: 4x4 grid of 16x16x32 MFMAs. LDS rows padded to 72 f16 (stride 36
// words -> 2-way bank aliasing = free). 16 K-iterations.
// ---------------------------------------------------------------------------
__global__ __launch_bounds__(256) void gemm_h(const _Float16* __restrict__ Ah,
                                              const _Float16* __restrict__ Wh,
                                              float* __restrict__ C, float scale) {
  __shared__ _Float16 As[128][72];
  __shared__ _Float16 Bs[128][72];
  const int tid  = threadIdx.x;
  const int m0   = blockIdx.x * 128;
  const int n0   = blockIdx.y * 128;
  const int wid  = tid >> 6;       // wave 0..3
  const int wm   = wid & 1;        // wave row (0..1) -> 64 rows
  const int wn   = wid >> 1;       // wave col (0..1) -> 64 cols
  const int lane = tid & 63;
  const int l15  = lane & 15;
  const int quad = lane >> 4;      // 0..3

  v4f acc[4][4] = {};

  for (int k0 = 0; k0 < 1024; k0 += 64) {
    // stage A and B tiles: 128 rows x 8 chunks of 8 f16 each; 4 chunks/thread
#pragma unroll
    for (int i = 0; i < 4; ++i) {
      int c  = i * 256 + tid;      // 0..1023
      int r  = c >> 3;             // 0..127
      int ch = (c & 7) * 8;        // 0..56
      *(v8h*)&As[r][ch] = *(const v8h*)&Ah[(size_t)(m0 + r) * 1024 + k0 + ch];
      *(v8h*)&Bs[r][ch] = *(const v8h*)&Wh[(size_t)(n0 + r) * 1024 + k0 + ch];
    }
    __syncthreads();
#pragma unroll
    for (int kk = 0; kk < 2; ++kk) {   // two K=32 MFMA steps
      v8h af[4], bf[4];
#pragma unroll
      for (int i = 0; i < 4; ++i)
        af[i] = *(const v8h*)&As[wm * 64 + i * 16 + l15][kk * 32 + quad * 8];
#pragma unroll
      for (int j = 0; j < 4; ++j)
        bf[j] = *(const v8h*)&Bs[wn * 64 + j * 16 + l15][kk * 32 + quad * 8];
#pragma unroll
      for (int i = 0; i < 4; ++i)
#pragma unroll
        for (int j = 0; j < 4; ++j)
          acc[i][j] = __builtin_amdgcn_mfma_f32_16x16x32_f16(af[i], bf[j], acc[i][j], 0, 0, 0);
    }
    __syncthreads();
  }

  // epilogue: C/D layout col=lane&15, row=quad*4+reg
#pragma unroll
  for (int i = 0; i < 4; ++i) {
    const size_t mrow = (size_t)(m0 + wm * 64 + i * 16 + quad * 4);
#pragma unroll
    for (int j = 0; j < 4; ++j) {
      const int ncol = n0 + wn * 64 + j * 16 + l15;
#pragma unroll
      for (int r = 0; r < 4; ++r)
        C[(mrow + r) * 1024 + ncol] = acc[i][j][r] * scale;
    }
  }
}

// ---------------------------------------------------------------------------
// Attention pass 1: logits = Q_head . M_k^T / 8, softmax over S, write g_P,
// write per-tile colsum partials. Block = one (b,h) x 64-token tile, 256 thr.
// ---------------------------------------------------------------------------
__global__ __launch_bounds__(256) void attn_softmax_colsum(
    const float* __restrict__ Mk) {
  __shared__ float QsT[64][68];    // [d][t]
  __shared__ float MkT[32][257];   // [d-chunk][s]
  __shared__ float csum_sh[256];
  const int tid = threadIdx.x;
  const int bh  = blockIdx.x;      // b*16 + h
  const int b   = bh >> 4, h = bh & 15;
  const int t0  = blockIdx.y * 64;
  const int tg  = tid >> 5;        // 0..7
  const int sg  = tid & 31;        // 0..31

  csum_sh[tid] = 0.0f;
#pragma unroll
  for (int i = 0; i < 4; ++i) {
    int c  = i * 256 + tid;
    int t  = c >> 4;
    int dc = (c & 15) * 4;
    float4 v = *(const float4*)&g_Q[(size_t)(b * T_ + t0 + t) * 1024 + h * 64 + dc];
    QsT[dc + 0][t] = v.x; QsT[dc + 1][t] = v.y;
    QsT[dc + 2][t] = v.z; QsT[dc + 3][t] = v.w;
  }

  float acc[8][8] = {};
  for (int dchunk = 0; dchunk < 2; ++dchunk) {
    __syncthreads();
#pragma unroll
    for (int i = 0; i < 8; ++i) {
      int c  = i * 256 + tid;
      int s  = c >> 3;
      int dc = (c & 7) * 4;
      float4 v = *(const float4*)&Mk[(size_t)(h * 256 + s) * 64 + dchunk * 32 + dc];
      MkT[dc + 0][s] = v.x; MkT[dc + 1][s] = v.y;
      MkT[dc + 2][s] = v.z; MkT[dc + 3][s] = v.w;
    }
    __syncthreads();
    for (int d = 0; d < 32; ++d) {
      float q[8], mk[8];
      *(float4*)&q[0] = *(const float4*)&QsT[dchunk * 32 + d][tg * 8];
      *(float4*)&q[4] = *(const float4*)&QsT[dchunk * 32 + d][tg * 8 + 4];
#pragma unroll
      for (int j = 0; j < 8; ++j) mk[j] = MkT[d][sg + 32 * j];
#pragma unroll
      for (int i = 0; i < 8; ++i)
#pragma unroll
        for (int j = 0; j < 8; ++j)
          acc[i][j] = fmaf(q[i], mk[j], acc[i][j]);
    }
  }

  const float scale = 0.125f;
  float colacc[8] = {};
#pragma unroll
  for (int i = 0; i < 8; ++i) {
    float m = -INFINITY;
#pragma unroll
    for (int j = 0; j < 8; ++j) { acc[i][j] *= scale; m = fmaxf(m, acc[i][j]); }
#pragma unroll
    for (int off = 16; off >= 1; off >>= 1) m = fmaxf(m, __shfl_xor(m, off));
    float ssum = 0.0f;
#pragma unroll
    for (int j = 0; j < 8; ++j) { acc[i][j] = expf(acc[i][j] - m); ssum += acc[i][j]; }
#pragma unroll
    for (int off = 16; off >= 1; off >>= 1) ssum += __shfl_xor(ssum, off);
    const float inv = 1.0f / ssum;
    const int t = t0 + tg * 8 + i;
    float* Prow = &g_P[((size_t)bh * T_ + t) * 256];
#pragma unroll
    for (int j = 0; j < 8; ++j) {
      float p = acc[i][j] * inv;
      Prow[sg + 32 * j] = p;
      colacc[j] += p;
    }
  }
#pragma unroll
  for (int j = 0; j < 8; ++j) atomicAdd(&csum_sh[sg + 32 * j], colacc[j]);
  __syncthreads();
  g_cpart[((size_t)bh * NTILE_ + blockIdx.y) * 256 + tid] = csum_sh[tid];
}

// ---------------------------------------------------------------------------
// Fold the 64 per-tile partials into 1/(colsum + 1e-6).
// ---------------------------------------------------------------------------
__global__ __launch_bounds__(256) void reduce_colsum() {
  const int bh = blockIdx.x;
  const int s  = threadIdx.x;
  float acc = 0.0f;
#pragma unroll 8
  for (int k = 0; k < NTILE_; ++k)
    acc += g_cpart[((size_t)bh * NTILE_ + k) * 256 + s];
  g_colsum_inv[bh * 256 + s] = 1.0f / (acc + 1e-6f);
}

// ---------------------------------------------------------------------------
// out_pre[b,t,h*64+d] = sum_s g_P * colsum_inv * Mv.  Writes fp16 out_pre*512
// into g_AH (x_h is dead after gemm_q). 64x64 tile, 4x4/thread.
// ---------------------------------------------------------------------------
__global__ __launch_bounds__(256) void pv_norm(const float* __restrict__ Mv) {
  __shared__ float Ps[64][64];
  __shared__ float Mvs[64][64];
  __shared__ float inv_sh[256];
  const int tid = threadIdx.x;
  const int bh  = blockIdx.x;
  const int b   = bh >> 4, h = bh & 15;
  const int t0  = blockIdx.y * 64;
  const int tg  = tid >> 4;
  const int dg  = tid & 15;
  inv_sh[tid] = g_colsum_inv[bh * 256 + tid];

  float acc[4][4] = {};
  for (int sc = 0; sc < 4; ++sc) {
    __syncthreads();
#pragma unroll
    for (int i = 0; i < 4; ++i) {
      int c   = i * 256 + tid;
      int t   = c >> 4;
      int scl = (c & 15) * 4;
      float4 v = *(const float4*)&g_P[((size_t)bh * T_ + t0 + t) * 256 + sc * 64 + scl];
      Ps[t][scl + 0] = v.x * inv_sh[sc * 64 + scl + 0];
      Ps[t][scl + 1] = v.y * inv_sh[sc * 64 + scl + 1];
      Ps[t][scl + 2] = v.z * inv_sh[sc * 64 + scl + 2];
      Ps[t][scl + 3] = v.w * inv_sh[sc * 64 + scl + 3];
    }
#pragma unroll
    for (int i = 0; i < 4; ++i) {
      int c   = i * 256 + tid;
      int s   = c >> 4;
      int dcl = (c & 15) * 4;
      float4 v = *(const float4*)&Mv[((size_t)h * 256 + sc * 64 + s) * 64 + dcl];
      *(float4*)&Mvs[s][dcl] = v;
    }
    __syncthreads();
    for (int s = 0; s < 64; ++s) {
      float p0 = Ps[tg * 4 + 0][s];
      float p1 = Ps[tg * 4 + 1][s];
      float p2 = Ps[tg * 4 + 2][s];
      float p3 = Ps[tg * 4 + 3][s];
      float4 mv = *(const float4*)&Mvs[s][dg * 4];
      acc[0][0] = fmaf(p0, mv.x, acc[0][0]); acc[0][1] = fmaf(p0, mv.y, acc[0][1]);
      acc[0][2] = fmaf(p0, mv.z, acc[0][2]); acc[0][3] = fmaf(p0, mv.w, acc[0][3]);
      acc[1][0] = fmaf(p1, mv.x, acc[1][0]); acc[1][1] = fmaf(p1, mv.y, acc[1][1]);
      acc[1][2] = fmaf(p1, mv.z, acc[1][2]); acc[1][3] = fmaf(p1, mv.w, acc[1][3]);
      acc[2][0] = fmaf(p2, mv.x, acc[2][0]); acc[2][1] = fmaf(p2, mv.y, acc[2][1]);
      acc[2][2] = fmaf(p2, mv.z, acc[2][2]); acc[2][3] = fmaf(p2, mv.w, acc[2][3]);
      acc[3][0] = fmaf(p3, mv.x, acc[3][0]); acc[3][1] = fmaf(p3, mv.y, acc[3][1]);
      acc[3][2] = fmaf(p3, mv.z, acc[3][2]); acc[3][3] = fmaf(p3, mv.w, acc[3][3]);
    }
  }
  // write fp16 out_pre, scaled by 512 to stay in fp16-normal range
#pragma unroll
  for (int i = 0; i < 4; ++i) {
    v4h o;
    o[0] = (_Float16)(acc[i][0] * 512.0f);
    o[1] = (_Float16)(acc[i][1] * 512.0f);
    o[2] = (_Float16)(acc[i][2] * 512.0f);
    o[3] = (_Float16)(acc[i][3] * 512.0f);
    *(v4h*)&g_AH[(size_t)(b * T_ + t0 + tg * 4 + i) * 1024 + h * 64 + dg * 4] = o;
  }
}

// ---------------------------------------------------------------------------
// Pipeline:
//   cvt x->g_AH, Wq->g_WqH, Wo->g_WoH (fp16)
//   gemm_h(g_AH, g_WqH) -> g_Q           [MFMA]
//   attn(Mk)            -> g_P, g_cpart
//   reduce              -> g_colsum_inv
//   pv(Mv)              -> g_AH (fp16 out_pre * 512)
//   gemm_h(g_AH, g_WoH, scale=1/512) -> d_out   [MFMA]
// ---------------------------------------------------------------------------
extern "C" void kernel_launch(void* const* d_in, const int* in_sizes, int n_in,
                              void* d_out, int out_size, void* d_ws, size_t ws_size,
                              hipStream_t stream) {
  const float* x  = (const float*)d_in[0];
  const float* Wq = (const float*)d_in[1];
  const float* Wo = (const float*)d_in[2];
  const float* Mk = (const float*)d_in[3];
  const float* Mv = (const float*)d_in[4];
  float* out = (float*)d_out;

  _Float16 *AH, *WqH, *WoH; float *Q;
  (void)hipGetSymbolAddress((void**)&AH,  HIP_SYMBOL(g_AH));
  (void)hipGetSymbolAddress((void**)&WqH, HIP_SYMBOL(g_WqH));
  (void)hipGetSymbolAddress((void**)&WoH, HIP_SYMBOL(g_WoH));
  (void)hipGetSymbolAddress((void**)&Q,   HIP_SYMBOL(g_Q));

  cvt_h<<<8192, 256, 0, stream>>>(x,  AH);    // 16,777,216 / 2048
  cvt_h<<<512,  256, 0, stream>>>(Wq, WqH);   //  1,048,576 / 2048
  cvt_h<<<512,  256, 0, stream>>>(Wo, WoH);
  gemm_h<<<dim3(BT_ / 128, DM_ / 128), 256, 0, stream>>>(AH, WqH, Q, 1.0f);
  attn_softmax_colsum<<<dim3(B_ * H_, NTILE_), 256, 0, stream>>>(Mk);
  reduce_colsum<<<dim3(B_ * H_), 256, 0, stream>>>();
  pv_norm<<<dim3(B_ * H_, NTILE_), 256, 0, stream>>>(Mv);
  gemm_h<<<dim3(BT_ / 128, DM_ / 128), 256, 0, stream>>>(AH, WoH, out, 1.0f / 512.0f);
}

// Round 6
// 453.671 us; speedup vs baseline: 2.7961x; 1.2218x over previous
//
#include <hip/hip_runtime.h>
#include <math.h>

// Problem constants (B=4, T=4096, D_MODEL=1024, H=16, D_HEAD=64, MEM=256)
constexpr int B_  = 4;
constexpr int T_  = 4096;
constexpr int DM_ = 1024;
constexpr int H_  = 16;
constexpr int S_  = 256;
constexpr int BT_ = B_ * T_;                    // 16384
constexpr int NTILE_ = T_ / 64;                 // 64 token-tiles per (b,h)
constexpr size_t QELEMS = (size_t)BT_ * DM_;    // 16,777,216

typedef _Float16 v8h __attribute__((ext_vector_type(8)));
typedef _Float16 v4h __attribute__((ext_vector_type(4)));
typedef float    v4f __attribute__((ext_vector_type(4)));

// Static device scratch; every element rewritten each call before any read.
__device__ _Float16 g_AH[QELEMS];        // fp16 x, later rewritten as fp16 out_pre*512
__device__ _Float16 g_QH[QELEMS];        // fp16 Q projection
__device__ _Float16 g_WqH[DM_ * DM_];    // fp16 Wq
__device__ _Float16 g_WoH[DM_ * DM_];    // fp16 Wo
__device__ _Float16 g_MkH[H_ * S_ * 64]; // fp16 Mk (row-major [h][s][d])
__device__ _Float16 g_MvT[H_ * 64 * S_]; // fp16 Mv transposed: [h][d][s]
__device__ float    g_cpart[(size_t)B_ * H_ * NTILE_ * S_];
__device__ float    g_colsum_inv[B_ * H_ * S_];

// ---------------------------------------------------------------------------
// fp32 -> fp16 conversion, 8 elems/thread.
// ---------------------------------------------------------------------------
__global__ __launch_bounds__(256) void cvt_h(const float* __restrict__ src,
                                             _Float16* __restrict__ dst) {
  const size_t i = (size_t)blockIdx.x * 256 + threadIdx.x;
  const float4* s = (const float4*)src;
  float4 a = s[2 * i], b = s[2 * i + 1];
  v8h o;
  o[0] = (_Float16)a.x; o[1] = (_Float16)a.y; o[2] = (_Float16)a.z; o[3] = (_Float16)a.w;
  o[4] = (_Float16)b.x; o[5] = (_Float16)b.y; o[6] = (_Float16)b.z; o[7] = (_Float16)b.w;
  *(v8h*)&dst[8 * i] = o;
}

// ---------------------------------------------------------------------------
// Mv fp32 [h][s][d] -> fp16 transposed [h][d][s]. 262144 elems, 1024 blocks.
// ---------------------------------------------------------------------------
__global__ __launch_bounds__(256) void transpose_mv(const float* __restrict__ Mv) {
  const int idx = blockIdx.x * 256 + threadIdx.x;
  const int h = idx >> 14, rem = idx & 16383;
  const int s = rem >> 6, d = rem & 63;
  g_MvT[h * 16384 + d * 256 + s] = (_Float16)Mv[idx];
}

// ---------------------------------------------------------------------------
// MFMA GEMM body: C = scale * A @ W^T, fp16 in. 128x128 tile, BK=64,
// 256 thr = 4 waves (2x2), each wave 4x4 of 16x16x32 MFMAs.
// FP16OUT: write _Float16, else float.
// ---------------------------------------------------------------------------
template <typename OUT_T>
__device__ __forceinline__ void gemm_body(const _Float16* __restrict__ Ah,
                                          const _Float16* __restrict__ Wh,
                                          OUT_T* __restrict__ C, float scale) {
  __shared__ _Float16 As[128][72];
  __shared__ _Float16 Bs[128][72];
  const int tid  = threadIdx.x;
  const int m0   = blockIdx.x * 128;
  const int n0   = blockIdx.y * 128;
  const int wid  = tid >> 6;
  const int wm   = wid & 1;
  const int wn   = wid >> 1;
  const int lane = tid & 63;
  const int l15  = lane & 15;
  const int quad = lane >> 4;

  v4f acc[4][4] = {};

  for (int k0 = 0; k0 < 1024; k0 += 64) {
#pragma unroll
    for (int i = 0; i < 4; ++i) {
      int c  = i * 256 + tid;
      int r  = c >> 3;
      int ch = (c & 7) * 8;
      *(v8h*)&As[r][ch] = *(const v8h*)&Ah[(size_t)(m0 + r) * 1024 + k0 + ch];
      *(v8h*)&Bs[r][ch] = *(const v8h*)&Wh[(size_t)(n0 + r) * 1024 + k0 + ch];
    }
    __syncthreads();
#pragma unroll
    for (int kk = 0; kk < 2; ++kk) {
      v8h af[4], bf[4];
#pragma unroll
      for (int i = 0; i < 4; ++i)
        af[i] = *(const v8h*)&As[wm * 64 + i * 16 + l15][kk * 32 + quad * 8];
#pragma unroll
      for (int j = 0; j < 4; ++j)
        bf[j] = *(const v8h*)&Bs[wn * 64 + j * 16 + l15][kk * 32 + quad * 8];
#pragma unroll
      for (int i = 0; i < 4; ++i)
#pragma unroll
        for (int j = 0; j < 4; ++j)
          acc[i][j] = __builtin_amdgcn_mfma_f32_16x16x32_f16(af[i], bf[j], acc[i][j], 0, 0, 0);
    }
    __syncthreads();
  }
#pragma unroll
  for (int i = 0; i < 4; ++i) {
    const size_t mrow = (size_t)(m0 + wm * 64 + i * 16 + quad * 4);
#pragma unroll
    for (int j = 0; j < 4; ++j) {
      const int ncol = n0 + wn * 64 + j * 16 + l15;
#pragma unroll
      for (int r = 0; r < 4; ++r)
        C[(mrow + r) * 1024 + ncol] = (OUT_T)(acc[i][j][r] * scale);
    }
  }
}

__global__ __launch_bounds__(256) void gemm_q16(const _Float16* __restrict__ Wq) {
  gemm_body<_Float16>(g_AH, Wq, g_QH, 1.0f);
}
__global__ __launch_bounds__(256) void gemm_o(const _Float16* __restrict__ Wo,
                                              float* __restrict__ out) {
  gemm_body<float>(g_AH, Wo, out, 1.0f / 512.0f);
}

// ---------------------------------------------------------------------------
// Shared QK+softmax micro-structure (per wave, 16 tokens x all 256 s):
// A-frag: Q[t = t0+wid*16+l15][kk*32+quad*8 ..+8]  (direct global v8h)
// B-frag: Mk[h][st*16+l15][kk*32+quad*8 ..+8]      (direct global v8h)
// Output C-layout: row(token) = quad*4+r, col(s) = st*16+l15.
// Row softmax: per-lane partial over 16 stiles, shfl_xor 1/2/4/8 over l15.
// ---------------------------------------------------------------------------
#define QK_SOFTMAX(P_ACC)                                                     \
  {                                                                           \
    v8h af[2];                                                                \
    const _Float16* qrow = &g_QH[(size_t)(b * T_ + t0 + wid * 16 + l15) * 1024 + h * 64]; \
    af[0] = *(const v8h*)&qrow[quad * 8];                                     \
    af[1] = *(const v8h*)&qrow[32 + quad * 8];                                \
    const _Float16* mkh = &g_MkH[h * (S_ * 64)];                              \
    _Pragma("unroll")                                                         \
    for (int st = 0; st < 16; ++st) {                                         \
      const _Float16* mkrow = &mkh[(st * 16 + l15) * 64];                     \
      v8h b0 = *(const v8h*)&mkrow[quad * 8];                                 \
      v8h b1 = *(const v8h*)&mkrow[32 + quad * 8];                            \
      P_ACC[st] = __builtin_amdgcn_mfma_f32_16x16x32_f16(af[0], b0, P_ACC[st], 0, 0, 0); \
      P_ACC[st] = __builtin_amdgcn_mfma_f32_16x16x32_f16(af[1], b1, P_ACC[st], 0, 0, 0); \
    }                                                                         \
    _Pragma("unroll")                                                         \
    for (int r = 0; r < 4; ++r) {                                             \
      float m = -INFINITY;                                                    \
      _Pragma("unroll")                                                       \
      for (int st = 0; st < 16; ++st) {                                       \
        P_ACC[st][r] *= 0.125f;                                               \
        m = fmaxf(m, P_ACC[st][r]);                                           \
      }                                                                       \
      m = fmaxf(m, __shfl_xor(m, 1)); m = fmaxf(m, __shfl_xor(m, 2));         \
      m = fmaxf(m, __shfl_xor(m, 4)); m = fmaxf(m, __shfl_xor(m, 8));         \
      float ssum = 0.0f;                                                      \
      _Pragma("unroll")                                                       \
      for (int st = 0; st < 16; ++st) {                                       \
        float p = __expf(P_ACC[st][r] - m);                                   \
        P_ACC[st][r] = p; ssum += p;                                          \
      }                                                                       \
      ssum += __shfl_xor(ssum, 1); ssum += __shfl_xor(ssum, 2);               \
      ssum += __shfl_xor(ssum, 4); ssum += __shfl_xor(ssum, 8);               \
      const float inv = 1.0f / ssum;                                          \
      _Pragma("unroll")                                                       \
      for (int st = 0; st < 16; ++st) P_ACC[st][r] *= inv;                    \
    }                                                                         \
  }

// ---------------------------------------------------------------------------
// Pass 1: per-(bh, 64-token-tile) column-sum partials. No P materialization.
// ---------------------------------------------------------------------------
__global__ __launch_bounds__(256) void attn_colsum() {
  __shared__ float csum_sh[4][256];
  const int tid  = threadIdx.x;
  const int bh   = blockIdx.x;
  const int b    = bh >> 4, h = bh & 15;
  const int t0   = blockIdx.y * 64;
  const int wid  = tid >> 6;
  const int lane = tid & 63;
  const int l15  = lane & 15;
  const int quad = lane >> 4;

  v4f acc[16] = {};
  QK_SOFTMAX(acc);

  // column partials: col = st*16+l15; sum 4 regs, then across quads
#pragma unroll
  for (int st = 0; st < 16; ++st) {
    float c = acc[st][0] + acc[st][1] + acc[st][2] + acc[st][3];
    c += __shfl_xor(c, 16);
    c += __shfl_xor(c, 32);
    if (quad == 0) csum_sh[wid][st * 16 + l15] = c;
  }
  __syncthreads();
  g_cpart[((size_t)bh * NTILE_ + blockIdx.y) * 256 + tid] =
      csum_sh[0][tid] + csum_sh[1][tid] + csum_sh[2][tid] + csum_sh[3][tid];
}

// ---------------------------------------------------------------------------
// Fold the 64 per-tile partials into 1/(colsum + 1e-6).
// ---------------------------------------------------------------------------
__global__ __launch_bounds__(256) void reduce_colsum() {
  const int bh = blockIdx.x;
  const int s  = threadIdx.x;
  float acc = 0.0f;
#pragma unroll 8
  for (int k = 0; k < NTILE_; ++k)
    acc += g_cpart[((size_t)bh * NTILE_ + k) * 256 + s];
  g_colsum_inv[bh * 256 + s] = 1.0f / (acc + 1e-6f);
}

// ---------------------------------------------------------------------------
// Pass 2: recompute P, apply colsum_inv, LDS round-trip to A-layout, P@Mv via
// MFMA (B-frags straight from global g_MvT, L2-resident). Writes fp16
// out_pre*512 into g_AH.
// ---------------------------------------------------------------------------
__global__ __launch_bounds__(256) void pv_fused() {
  __shared__ _Float16 Psh[64][272];   // row stride 544B = 8-bank offset
  const int tid  = threadIdx.x;
  const int bh   = blockIdx.x;
  const int b    = bh >> 4, h = bh & 15;
  const int t0   = blockIdx.y * 64;
  const int wid  = tid >> 6;
  const int lane = tid & 63;
  const int l15  = lane & 15;
  const int quad = lane >> 4;

  v4f acc[16] = {};
  QK_SOFTMAX(acc);

  // normalize columns and stash fp16 P in LDS (C-layout -> [t][s])
#pragma unroll
  for (int st = 0; st < 16; ++st) {
    const float cinv = g_colsum_inv[bh * 256 + st * 16 + l15];
#pragma unroll
    for (int r = 0; r < 4; ++r)
      Psh[wid * 16 + quad * 4 + r][st * 16 + l15] = (_Float16)(acc[st][r] * cinv);
  }
  __syncthreads();

  // PV: out[16t x 64d] per wave; A-frag from Psh, B-frag from g_MvT global
  v8h af[8];
#pragma unroll
  for (int kc = 0; kc < 8; ++kc)
    af[kc] = *(const v8h*)&Psh[wid * 16 + l15][kc * 32 + quad * 8];

  const _Float16* mvt = &g_MvT[h * 16384];
  v4f oacc[4] = {};
#pragma unroll
  for (int nt = 0; nt < 4; ++nt) {
    const _Float16* mvrow = &mvt[(nt * 16 + l15) * 256];
#pragma unroll
    for (int kc = 0; kc < 8; ++kc) {
      v8h bf = *(const v8h*)&mvrow[kc * 32 + quad * 8];
      oacc[nt] = __builtin_amdgcn_mfma_f32_16x16x32_f16(af[kc], bf, oacc[nt], 0, 0, 0);
    }
  }

  // epilogue: t = t0+wid*16+quad*4+r, d = nt*16+l15; write fp16 out_pre*512
#pragma unroll
  for (int nt = 0; nt < 4; ++nt) {
#pragma unroll
    for (int r = 0; r < 4; ++r) {
      const int t = t0 + wid * 16 + quad * 4 + r;
      g_AH[(size_t)(b * T_ + t) * 1024 + h * 64 + nt * 16 + l15] =
          (_Float16)(oacc[nt][r] * 512.0f);
    }
  }
}

// ---------------------------------------------------------------------------
// Pipeline:
//   cvt x->g_AH, Wq->g_WqH, Wo->g_WoH, Mk->g_MkH; transpose Mv->g_MvT
//   gemm_q16: g_AH @ WqH^T -> g_QH (fp16)          [MFMA]
//   attn_colsum -> g_cpart;  reduce -> g_colsum_inv
//   pv_fused (recompute QK+softmax, P@Mv) -> g_AH (fp16 out_pre*512)
//   gemm_o: g_AH @ WoH^T * (1/512) -> d_out        [MFMA]
// ---------------------------------------------------------------------------
extern "C" void kernel_launch(void* const* d_in, const int* in_sizes, int n_in,
                              void* d_out, int out_size, void* d_ws, size_t ws_size,
                              hipStream_t stream) {
  const float* x  = (const float*)d_in[0];
  const float* Wq = (const float*)d_in[1];
  const float* Wo = (const float*)d_in[2];
  const float* Mk = (const float*)d_in[3];
  const float* Mv = (const float*)d_in[4];
  float* out = (float*)d_out;

  _Float16 *AH, *WqH, *WoH, *MkH;
  (void)hipGetSymbolAddress((void**)&AH,  HIP_SYMBOL(g_AH));
  (void)hipGetSymbolAddress((void**)&WqH, HIP_SYMBOL(g_WqH));
  (void)hipGetSymbolAddress((void**)&WoH, HIP_SYMBOL(g_WoH));
  (void)hipGetSymbolAddress((void**)&MkH, HIP_SYMBOL(g_MkH));

  cvt_h<<<8192, 256, 0, stream>>>(x,  AH);    // 16,777,216 / 2048
  cvt_h<<<512,  256, 0, stream>>>(Wq, WqH);
  cvt_h<<<512,  256, 0, stream>>>(Wo, WoH);
  cvt_h<<<128,  256, 0, stream>>>(Mk, MkH);   //    262,144 / 2048
  transpose_mv<<<1024, 256, 0, stream>>>(Mv);
  gemm_q16<<<dim3(BT_ / 128, DM_ / 128), 256, 0, stream>>>(WqH);
  attn_colsum<<<dim3(B_ * H_, NTILE_), 256, 0, stream>>>();
  reduce_colsum<<<dim3(B_ * H_), 256, 0, stream>>>();
  pv_fused<<<dim3(B_ * H_, NTILE_), 256, 0, stream>>>();
  gemm_o<<<dim3(BT_ / 128, DM_ / 128), 256, 0, stream>>>(WoH, out);
}